// Round 1
// baseline (75.641 us; speedup 1.0000x reference)
//
#include <hip/hip_runtime.h>
#include <hip/hip_bf16.h>

#define BB 2
#define CC 320
#define HH 64
#define WW 128
#define MAXDISP 48
#define GG 40
#define CPG 8     // channels per group = C / G
#define CR 20     // C / R

// -------------------------------------------------------------------------
// Kernel 1: global average pool over H*W for each (img, b, c) row.
// grid = 2*B*C = 1280 blocks, 256 threads. Row = 8192 floats = 2048 float4.
// -------------------------------------------------------------------------
__global__ __launch_bounds__(256) void gap_kernel(
    const float* __restrict__ ref, const float* __restrict__ tgt,
    float* __restrict__ gap /* [2][B][C] */) {
  int bid = blockIdx.x;            // 0 .. 1280
  int img = bid / (BB * CC);       // 0/1
  int rc  = bid - img * (BB * CC); // b*C + c
  const float* src = (img ? tgt : ref) + (size_t)rc * (HH * WW);
  const float4* v = reinterpret_cast<const float4*>(src);
  float acc = 0.f;
  for (int i = threadIdx.x; i < (HH * WW) / 4; i += 256) {
    float4 x = v[i];
    acc += (x.x + x.y) + (x.z + x.w);
  }
  // wave64 reduce
  for (int off = 32; off; off >>= 1) acc += __shfl_down(acc, off, 64);
  __shared__ float part[4];
  if ((threadIdx.x & 63) == 0) part[threadIdx.x >> 6] = acc;
  __syncthreads();
  if (threadIdx.x == 0) {
    float s = (part[0] + part[1]) + (part[2] + part[3]);
    gap[bid] = s * (1.0f / (HH * WW));
  }
}

// -------------------------------------------------------------------------
// Kernel 2: CMCAM channel attention (two tiny FCs) -> fused weights.
// One block, 128 threads. alpha = m_ref*m_tgt/8, beta = (1-m_ref)(1-m_tgt)/8
// (the /8 folds the group-mean of the volume kernel).
// -------------------------------------------------------------------------
__global__ __launch_bounds__(128) void mask_kernel(
    const float* __restrict__ gap,  // [2][B][C]
    const float* __restrict__ w1, const float* __restrict__ b1,
    const float* __restrict__ w2, const float* __restrict__ b2,
    float* __restrict__ alpha, float* __restrict__ beta /* [B*C] */) {
  __shared__ float gs[2 * BB * CC];   // 1280
  __shared__ float hs[2 * BB * CR];   // 80
  __shared__ float ms[2 * BB * CC];   // 1280
  int tid = threadIdx.x;
  for (int i = tid; i < 2 * BB * CC; i += 128) gs[i] = gap[i];
  __syncthreads();
  if (tid < 2 * BB * CR) {            // 80 dots of length 320
    int j = tid % CR;
    int ib = tid / CR;                // img*B + b
    float s = b1[j];
    const float* wrow = w1 + j * CC;
    const float* grow = gs + ib * CC;
    for (int c = 0; c < CC; ++c) s += wrow[c] * grow[c];
    hs[tid] = s > 0.f ? s : 0.f;      // ReLU
  }
  __syncthreads();
  for (int i = tid; i < 2 * BB * CC; i += 128) {  // 1280 dots of length 20
    int c = i % CC;
    int ib = i / CC;
    float s = b2[c];
    const float* hrow = hs + ib * CR;
    const float* wrow = w2 + c * CR;
#pragma unroll
    for (int j = 0; j < CR; ++j) s += wrow[j] * hrow[j];
    ms[i] = 1.f / (1.f + expf(-s));   // sigmoid
  }
  __syncthreads();
  for (int i = tid; i < BB * CC; i += 128) {  // i = b*C + c
    float mr = ms[i];                 // img 0
    float mt = ms[BB * CC + i];       // img 1
    alpha[i] = mr * mt * 0.125f;
    beta[i]  = (1.f - mr) * (1.f - mt) * 0.125f;
  }
}

// -------------------------------------------------------------------------
// Kernel 3: both group-wise correlation volumes in one pass.
// block = (b, g, h-pair); 256 threads: hl = tid>>7, w = tid&127.
// tgt group-rows staged in LDS (channel-major: conflict-free), ref row in
// registers. out[b, g, d, h, w]   = sum_c ref*tgt_shift * alpha_c
//          out[b, G+g, d, h, w]  = sum_c ref*tgt_shift * beta_c
// -------------------------------------------------------------------------
__global__ __launch_bounds__(256) void volume_kernel(
    const float* __restrict__ ref, const float* __restrict__ tgt,
    const float* __restrict__ alpha, const float* __restrict__ beta,
    float* __restrict__ out) {
  __shared__ float Tl[2][CPG][WW];   // 8 KB
  const int H2 = HH / 2;
  int bid = blockIdx.x;              // b*(G*H2) + g*H2 + h2
  int b   = bid / (GG * H2);
  int rem = bid - b * (GG * H2);
  int g   = rem / H2;
  int h2  = rem - g * H2;
  int tid = threadIdx.x;
  int hl  = tid >> 7;
  int w   = tid & 127;
  int h   = h2 * 2 + hl;

  // stage tgt rows to LDS, ref rows to registers (each byte read once)
  size_t base = ((size_t)(b * CC + g * CPG) * HH + h) * WW + w;
  float rf[CPG];
#pragma unroll
  for (int c = 0; c < CPG; ++c) {
    rf[c] = ref[base + (size_t)c * (HH * WW)];
    Tl[hl][c][w] = tgt[base + (size_t)c * (HH * WW)];
  }
  float al[CPG], be[CPG];
#pragma unroll
  for (int c = 0; c < CPG; ++c) {
    al[c] = alpha[b * CC + g * CPG + c];
    be[c] = beta[b * CC + g * CPG + c];
  }
  __syncthreads();

  size_t out_hf = (((size_t)(b * 2 * GG + g) * MAXDISP) * HH + h) * WW + w;
  size_t out_ct = out_hf + (size_t)GG * MAXDISP * HH * WW;
#pragma unroll 4
  for (int d = 0; d < MAXDISP; ++d) {
    int wd = w - d;
    float mask = wd >= 0 ? 1.0f : 0.0f;
    int wc = wd >= 0 ? wd : 0;       // clamp: no divergence, no OOB
    float shf = 0.f, sct = 0.f;
#pragma unroll
    for (int c = 0; c < CPG; ++c) {
      float p = rf[c] * Tl[hl][c][wc];
      shf += p * al[c];
      sct += p * be[c];
    }
    out[out_hf] = shf * mask;
    out[out_ct] = sct * mask;
    out_hf += HH * WW;
    out_ct += HH * WW;
  }
}

// -------------------------------------------------------------------------
extern "C" void kernel_launch(void* const* d_in, const int* in_sizes, int n_in,
                              void* d_out, int out_size, void* d_ws, size_t ws_size,
                              hipStream_t stream) {
  const float* ref = (const float*)d_in[0];
  const float* tgt = (const float*)d_in[1];
  const float* w1  = (const float*)d_in[2];
  const float* b1  = (const float*)d_in[3];
  const float* w2  = (const float*)d_in[4];
  const float* b2  = (const float*)d_in[5];
  float* out = (float*)d_out;

  float* ws    = (float*)d_ws;
  float* gap   = ws;            // 1280 floats
  float* alpha = ws + 1280;     // 640
  float* beta  = ws + 1920;     // 640

  gap_kernel<<<2 * BB * CC, 256, 0, stream>>>(ref, tgt, gap);
  mask_kernel<<<1, 128, 0, stream>>>(gap, w1, b1, w2, b2, alpha, beta);
  volume_kernel<<<BB * GG * (HH / 2), 256, 0, stream>>>(ref, tgt, alpha, beta, out);
}

// Round 2
// 73.193 us; speedup vs baseline: 1.0334x; 1.0334x over previous
//
#include <hip/hip_runtime.h>
#include <hip/hip_bf16.h>

#define BB 2
#define CC 320
#define HH 64
#define WW 128
#define MAXDISP 48
#define GG 40
#define CPG 8     // channels per group = C / G
#define CR 20     // C / R

// -------------------------------------------------------------------------
// Kernel 1: global average pool over H*W for each (img, b, c) row.
// grid = 2*B*C = 1280 blocks, 256 threads. Row = 8192 floats = 2048 float4.
// Normal (caching) loads on purpose: leaves ref/tgt resident in L3 for the
// volume kernel.
// -------------------------------------------------------------------------
__global__ __launch_bounds__(256) void gap_kernel(
    const float* __restrict__ ref, const float* __restrict__ tgt,
    float* __restrict__ gap /* [2][B][C] */) {
  int bid = blockIdx.x;            // 0 .. 1280
  int img = bid / (BB * CC);       // 0/1
  int rc  = bid - img * (BB * CC); // b*C + c
  const float* src = (img ? tgt : ref) + (size_t)rc * (HH * WW);
  const float4* v = reinterpret_cast<const float4*>(src);
  float acc = 0.f;
  for (int i = threadIdx.x; i < (HH * WW) / 4; i += 256) {
    float4 x = v[i];
    acc += (x.x + x.y) + (x.z + x.w);
  }
  // wave64 reduce
  for (int off = 32; off; off >>= 1) acc += __shfl_down(acc, off, 64);
  __shared__ float part[4];
  if ((threadIdx.x & 63) == 0) part[threadIdx.x >> 6] = acc;
  __syncthreads();
  if (threadIdx.x == 0) {
    float s = (part[0] + part[1]) + (part[2] + part[3]);
    gap[bid] = s * (1.0f / (HH * WW));
  }
}

// -------------------------------------------------------------------------
// Kernel 2: CMCAM channel attention (two tiny FCs) -> fused weights.
// One block, 128 threads. alpha = m_ref*m_tgt/8, beta = (1-m_ref)(1-m_tgt)/8
// (the /8 folds the group-mean of the volume kernel).
// -------------------------------------------------------------------------
__global__ __launch_bounds__(128) void mask_kernel(
    const float* __restrict__ gap,  // [2][B][C]
    const float* __restrict__ w1, const float* __restrict__ b1,
    const float* __restrict__ w2, const float* __restrict__ b2,
    float* __restrict__ alpha, float* __restrict__ beta /* [B*C] */) {
  __shared__ float gs[2 * BB * CC];   // 1280
  __shared__ float hs[2 * BB * CR];   // 80
  __shared__ float ms[2 * BB * CC];   // 1280
  int tid = threadIdx.x;
  for (int i = tid; i < 2 * BB * CC; i += 128) gs[i] = gap[i];
  __syncthreads();
  if (tid < 2 * BB * CR) {            // 80 dots of length 320, float4
    int j = tid % CR;
    int ib = tid / CR;                // img*B + b
    float s = b1[j];
    const float4* wrow = reinterpret_cast<const float4*>(w1 + j * CC);
    const float4* grow = reinterpret_cast<const float4*>(gs + ib * CC);
#pragma unroll 4
    for (int c = 0; c < CC / 4; ++c) {
      float4 a = wrow[c], g = grow[c];
      s += a.x * g.x + a.y * g.y + a.z * g.z + a.w * g.w;
    }
    hs[tid] = s > 0.f ? s : 0.f;      // ReLU
  }
  __syncthreads();
  for (int i = tid; i < 2 * BB * CC; i += 128) {  // 1280 dots of length 20
    int c = i % CC;
    int ib = i / CC;
    float s = b2[c];
    const float* hrow = hs + ib * CR;
    const float* wrow = w2 + c * CR;
#pragma unroll
    for (int j = 0; j < CR; ++j) s += wrow[j] * hrow[j];
    ms[i] = 1.f / (1.f + expf(-s));   // sigmoid
  }
  __syncthreads();
  for (int i = tid; i < BB * CC; i += 128) {  // i = b*C + c
    float mr = ms[i];                 // img 0
    float mt = ms[BB * CC + i];       // img 1
    alpha[i] = mr * mt * 0.125f;
    beta[i]  = (1.f - mr) * (1.f - mt) * 0.125f;
  }
}

// -------------------------------------------------------------------------
// Kernel 3: both group-wise correlation volumes in one pass.
// block = (b, g, h-pair); 256 threads: hl = tid>>7, w = tid&127.
// tgt group-rows staged in LDS (channel-major: conflict-free); ref row
// pre-scaled by alpha/beta into registers (ra/rb), so inner loop is pure FMA.
// Non-temporal stores: output is write-once, never re-read -> keep ref/tgt
// resident in L3 instead of letting the write stream evict them.
// -------------------------------------------------------------------------
__global__ __launch_bounds__(256) void volume_kernel(
    const float* __restrict__ ref, const float* __restrict__ tgt,
    const float* __restrict__ alpha, const float* __restrict__ beta,
    float* __restrict__ out) {
  __shared__ float Tl[2][CPG][WW];   // 8 KB
  const int H2 = HH / 2;
  int bid = blockIdx.x;              // b*(G*H2) + g*H2 + h2
  int b   = bid / (GG * H2);
  int rem = bid - b * (GG * H2);
  int g   = rem / H2;
  int h2  = rem - g * H2;
  int tid = threadIdx.x;
  int hl  = tid >> 7;
  int w   = tid & 127;
  int h   = h2 * 2 + hl;

  // stage tgt rows to LDS, ref rows to registers (each byte read once)
  size_t base = ((size_t)(b * CC + g * CPG) * HH + h) * WW + w;
  float ra[CPG], rb[CPG];
#pragma unroll
  for (int c = 0; c < CPG; ++c) {
    float r = ref[base + (size_t)c * (HH * WW)];
    Tl[hl][c][w] = tgt[base + (size_t)c * (HH * WW)];
    float al = alpha[b * CC + g * CPG + c];
    float be = beta[b * CC + g * CPG + c];
    ra[c] = r * al;                  // fold alpha/8 into ref
    rb[c] = r * be;                  // fold beta/8 into ref
  }
  __syncthreads();

  size_t out_hf = (((size_t)(b * 2 * GG + g) * MAXDISP) * HH + h) * WW + w;
  size_t out_ct = out_hf + (size_t)GG * MAXDISP * HH * WW;
#pragma unroll 4
  for (int d = 0; d < MAXDISP; ++d) {
    int wd = w - d;
    float mask = wd >= 0 ? 1.0f : 0.0f;
    int wc = wd >= 0 ? wd : 0;       // clamp: no divergence, no OOB
    float shf = 0.f, sct = 0.f;
#pragma unroll
    for (int c = 0; c < CPG; ++c) {
      float t = Tl[hl][c][wc];
      shf += ra[c] * t;
      sct += rb[c] * t;
    }
    __builtin_nontemporal_store(shf * mask, &out[out_hf]);
    __builtin_nontemporal_store(sct * mask, &out[out_ct]);
    out_hf += HH * WW;
    out_ct += HH * WW;
  }
}

// -------------------------------------------------------------------------
extern "C" void kernel_launch(void* const* d_in, const int* in_sizes, int n_in,
                              void* d_out, int out_size, void* d_ws, size_t ws_size,
                              hipStream_t stream) {
  const float* ref = (const float*)d_in[0];
  const float* tgt = (const float*)d_in[1];
  const float* w1  = (const float*)d_in[2];
  const float* b1  = (const float*)d_in[3];
  const float* w2  = (const float*)d_in[4];
  const float* b2  = (const float*)d_in[5];
  float* out = (float*)d_out;

  float* ws    = (float*)d_ws;
  float* gap   = ws;            // 1280 floats
  float* alpha = ws + 1280;     // 640
  float* beta  = ws + 1920;     // 640

  gap_kernel<<<2 * BB * CC, 256, 0, stream>>>(ref, tgt, gap);
  mask_kernel<<<1, 128, 0, stream>>>(gap, w1, b1, w2, b2, alpha, beta);
  volume_kernel<<<BB * GG * (HH / 2), 256, 0, stream>>>(ref, tgt, alpha, beta, out);
}

// Round 4
// 65.598 us; speedup vs baseline: 1.1531x; 1.1158x over previous
//
#include <hip/hip_runtime.h>
#include <hip/hip_bf16.h>

#define BB 2
#define CC 320
#define HH 64
#define WW 128
#define MAXDISP 48
#define GG 40
#define CPG 8     // channels per group = C / G
#define CR 20     // C / R

typedef float fx4 __attribute__((ext_vector_type(4)));  // native vec for nt stores

// -------------------------------------------------------------------------
// Kernel 1: global average pool over H*W for each (img, b, c) row.
// Normal (caching) loads: leaves ref/tgt resident in L3 for volume_kernel.
// -------------------------------------------------------------------------
__global__ __launch_bounds__(256) void gap_kernel(
    const float* __restrict__ ref, const float* __restrict__ tgt,
    float* __restrict__ gap /* [2][B][C] */) {
  int bid = blockIdx.x;            // 0 .. 1280
  int img = bid / (BB * CC);       // 0/1
  int rc  = bid - img * (BB * CC); // b*C + c
  const float* src = (img ? tgt : ref) + (size_t)rc * (HH * WW);
  const float4* v = reinterpret_cast<const float4*>(src);
  float acc = 0.f;
  for (int i = threadIdx.x; i < (HH * WW) / 4; i += 256) {
    float4 x = v[i];
    acc += (x.x + x.y) + (x.z + x.w);
  }
  for (int off = 32; off; off >>= 1) acc += __shfl_down(acc, off, 64);
  __shared__ float part[4];
  if ((threadIdx.x & 63) == 0) part[threadIdx.x >> 6] = acc;
  __syncthreads();
  if (threadIdx.x == 0) {
    float s = (part[0] + part[1]) + (part[2] + part[3]);
    gap[bid] = s * (1.0f / (HH * WW));
  }
}

// -------------------------------------------------------------------------
// Kernel 2: CMCAM channel attention -> fused weights.
// alpha = m_ref*m_tgt/8, beta = (1-m_ref)(1-m_tgt)/8 (folds group-mean /8).
// FC1 parallelized: 2 threads per output dot + shfl_xor reduce.
// -------------------------------------------------------------------------
__global__ __launch_bounds__(256) void mask_kernel(
    const float* __restrict__ gap,  // [2][B][C]
    const float* __restrict__ w1, const float* __restrict__ b1,
    const float* __restrict__ w2, const float* __restrict__ b2,
    float* __restrict__ alpha, float* __restrict__ beta /* [B*C] */) {
  __shared__ float gs[2 * BB * CC];   // 1280
  __shared__ float hs[2 * BB * CR];   // 80
  __shared__ float ms[2 * BB * CC];   // 1280
  int tid = threadIdx.x;
  for (int i = tid; i < 2 * BB * CC; i += 256) gs[i] = gap[i];
  __syncthreads();
  if (tid < 2 * 2 * BB * CR) {        // 160 threads: pair per output
    int p = tid >> 1, half = tid & 1; // p in [0,80)
    int j = p % CR;
    int ib = p / CR;                  // img*B + b
    const float4* wrow = reinterpret_cast<const float4*>(w1 + j * CC);
    const float4* grow = reinterpret_cast<const float4*>(gs + ib * CC);
    float s = 0.f;
#pragma unroll 5
    for (int c = half * 40; c < half * 40 + 40; ++c) {
      float4 a = wrow[c], g = grow[c];
      s += a.x * g.x + a.y * g.y + a.z * g.z + a.w * g.w;
    }
    s += __shfl_xor(s, 1, 64);        // pair reduce (same wave)
    if (!half) {
      s += b1[j];
      hs[p] = s > 0.f ? s : 0.f;      // ReLU
    }
  }
  __syncthreads();
  for (int i = tid; i < 2 * BB * CC; i += 256) {  // 1280 dots of length 20
    int c = i % CC;
    int ib = i / CC;
    float s = b2[c];
    const float* hrow = hs + ib * CR;
    const float* wrow = w2 + c * CR;
#pragma unroll
    for (int j = 0; j < CR; ++j) s += wrow[j] * hrow[j];
    ms[i] = 1.f / (1.f + expf(-s));   // sigmoid
  }
  __syncthreads();
  for (int i = tid; i < BB * CC; i += 256) {  // i = b*C + c
    float mr = ms[i];
    float mt = ms[BB * CC + i];
    alpha[i] = mr * mt * 0.125f;
    beta[i]  = (1.f - mr) * (1.f - mt) * 0.125f;
  }
}

// -------------------------------------------------------------------------
// Kernel 3: both group-wise correlation volumes, register-ring version.
// block = (b, g, h2). 256 threads = dslot(4) x hl(2) x w4(32).
// Thread owns 4 consecutive w (wq=4*w4) and 12 consecutive d (d0=12*dslot).
// out[d][wq+j] = sum_c rf[c][j] * T[c][wq+j-d] * {alpha|beta}[c]
// Tap window [wq-d .. wq-d+3] slides by 1 per d-step -> 4-entry register
// ring per channel: 8 ds_read_b32 per step yield 8 outputs (2 float4 nt
// stores). LDS x-index XOR-swizzled (x ^ ((x>>5)&3)) to break the stride-4
// lane pattern's 8-way bank conflict; swizzle is within-16B so staging is
// one permuted ds_write_b128. Taps with x<0 are zeroed, which exactly
// produces the w<d zero region -- no output masks.
// -------------------------------------------------------------------------
__global__ __launch_bounds__(256) void volume_kernel(
    const float* __restrict__ ref, const float* __restrict__ tgt,
    const float* __restrict__ alpha, const float* __restrict__ beta,
    float* __restrict__ out) {
  __shared__ float Tl[2][CPG][WW];   // 8 KB, x-swizzled
  int bid = blockIdx.x;              // b*(G*32) + g*32 + h2
  int b   = bid / (GG * 32);
  int rem = bid - b * (GG * 32);
  int g   = rem >> 5;
  int h2  = rem & 31;
  int tid = threadIdx.x;
  int dslot = tid >> 6;              // 0..3 (= wave id)
  int hl    = (tid >> 5) & 1;
  int w4    = tid & 31;
  int wq    = w4 << 2;
  int d0    = dslot * 12;
  int h     = h2 * 2 + hl;

  // ---- stage tgt to LDS (swizzled). Staging role: c_s = tid>>5 (0..7),
  // each staging thread writes its quad for BOTH h rows.
  {
    int c_s = tid >> 5;
    int xq  = (tid & 31) << 2;
    int k   = (xq >> 5) & 3;         // swizzle key, constant over the quad
    size_t tb = ((size_t)((b * CC + g * CPG + c_s) * HH) + h2 * 2) * WW + xq;
    float4 v0 = *reinterpret_cast<const float4*>(tgt + tb);
    float4 v1 = *reinterpret_cast<const float4*>(tgt + tb + WW);
    // q[j'] = v[j' ^ k]  (XOR permutation: pair-swap then half-swap)
    float4 q0 = (k & 1) ? make_float4(v0.y, v0.x, v0.w, v0.z) : v0;
    q0 = (k & 2) ? make_float4(q0.z, q0.w, q0.x, q0.y) : q0;
    float4 q1 = (k & 1) ? make_float4(v1.y, v1.x, v1.w, v1.z) : v1;
    q1 = (k & 2) ? make_float4(q1.z, q1.w, q1.x, q1.y) : q1;
    *reinterpret_cast<float4*>(&Tl[0][c_s][xq]) = q0;
    *reinterpret_cast<float4*>(&Tl[1][c_s][xq]) = q1;
  }

  // ---- ref quad + weights into registers
  float rf[CPG][4];
  float al[CPG], be[CPG];
  size_t rbase = ((size_t)((b * CC + g * CPG) * HH) + h) * WW + wq;
#pragma unroll
  for (int c = 0; c < CPG; ++c) {
    float4 rv = *reinterpret_cast<const float4*>(ref + rbase + (size_t)c * (HH * WW));
    rf[c][0] = rv.x; rf[c][1] = rv.y; rf[c][2] = rv.z; rf[c][3] = rv.w;
    al[c] = alpha[b * CC + g * CPG + c];
    be[c] = beta[b * CC + g * CPG + c];
  }
  __syncthreads();

  // ---- prefill ring: slot r holds tap x = A + r
  const int A = wq - d0;
  float t[CPG][4];
#pragma unroll
  for (int r = 0; r < 4; ++r) {
    int x  = A + r;
    int xc = x < 0 ? 0 : x;
    int xs = xc ^ ((xc >> 5) & 3);
#pragma unroll
    for (int c = 0; c < CPG; ++c) {
      float v = Tl[hl][c][xs];
      t[c][r] = x < 0 ? 0.f : v;
    }
  }

  size_t o_hf = (((size_t)(b * 2 * GG + g) * MAXDISP + d0) * HH + h) * WW + wq;
  size_t o_ct = o_hf + (size_t)GG * MAXDISP * HH * WW;
#pragma unroll
  for (int i = 0; i < 12; ++i) {
    if (i > 0) {                     // slide window: new tap x = A - i
      int x  = A - i;
      int xc = x < 0 ? 0 : x;
      int xs = xc ^ ((xc >> 5) & 3);
      const int s = (16 - i) & 3;    // slot being replaced
#pragma unroll
      for (int c = 0; c < CPG; ++c) {
        float v = Tl[hl][c][xs];
        t[c][s] = x < 0 ? 0.f : v;
      }
    }
    float o0h = 0.f, o1h = 0.f, o2h = 0.f, o3h = 0.f;
    float o0c = 0.f, o1c = 0.f, o2c = 0.f, o3c = 0.f;
#pragma unroll
    for (int c = 0; c < CPG; ++c) {
      float p0 = rf[c][0] * t[c][(16 + 0 - i) & 3];
      float p1 = rf[c][1] * t[c][(16 + 1 - i) & 3];
      float p2 = rf[c][2] * t[c][(16 + 2 - i) & 3];
      float p3 = rf[c][3] * t[c][(16 + 3 - i) & 3];
      o0h += p0 * al[c]; o0c += p0 * be[c];
      o1h += p1 * al[c]; o1c += p1 * be[c];
      o2h += p2 * al[c]; o2c += p2 * be[c];
      o3h += p3 * al[c]; o3c += p3 * be[c];
    }
    fx4 vh = {o0h, o1h, o2h, o3h};
    fx4 vc = {o0c, o1c, o2c, o3c};
    __builtin_nontemporal_store(vh, reinterpret_cast<fx4*>(out + o_hf));
    __builtin_nontemporal_store(vc, reinterpret_cast<fx4*>(out + o_ct));
    o_hf += HH * WW;
    o_ct += HH * WW;
  }
}

// -------------------------------------------------------------------------
extern "C" void kernel_launch(void* const* d_in, const int* in_sizes, int n_in,
                              void* d_out, int out_size, void* d_ws, size_t ws_size,
                              hipStream_t stream) {
  const float* ref = (const float*)d_in[0];
  const float* tgt = (const float*)d_in[1];
  const float* w1  = (const float*)d_in[2];
  const float* b1  = (const float*)d_in[3];
  const float* w2  = (const float*)d_in[4];
  const float* b2  = (const float*)d_in[5];
  float* out = (float*)d_out;

  float* ws    = (float*)d_ws;
  float* gap   = ws;            // 1280 floats
  float* alpha = ws + 1280;     // 640
  float* beta  = ws + 1920;     // 640

  gap_kernel<<<2 * BB * CC, 256, 0, stream>>>(ref, tgt, gap);
  mask_kernel<<<1, 256, 0, stream>>>(gap, w1, b1, w2, b2, alpha, beta);
  volume_kernel<<<BB * GG * 32, 256, 0, stream>>>(ref, tgt, alpha, beta, out);
}